// Round 1
// baseline (496.597 us; speedup 1.0000x reference)
//
#include <hip/hip_runtime.h>

#define CI 32
#define CO 32

// Kernel 1: out[o][c] = bias[c]  (fully initializes d_out; poison-safe)
__global__ void bias_init_kernel(float* __restrict__ out,
                                 const float* __restrict__ bias,
                                 int total4) {
    int idx = blockIdx.x * blockDim.x + threadIdx.x;
    if (idx >= total4) return;
    ((float4*)out)[idx] = ((const float4*)bias)[idx & 7];
}

// Kernel 2: for each (k,p): out[out_map[k][p]] += features[in_map[k][p]] @ weight[k]
// blockIdx.y = k  -> weight pointer is wave-uniform -> weight loads scalarize
// (s_load + v_fmac with SGPR operand), no LDS/DS in the FMA loop.
__global__ __launch_bounds__(256, 2) void scatter_conv(
    const float* __restrict__ features,
    const float* __restrict__ weight,
    const int* __restrict__ in_map,
    const int* __restrict__ out_map,
    float* __restrict__ out,
    int P)
{
    const int k = blockIdx.y;
    const float* __restrict__ wk = weight + (size_t)k * (CI * CO);
    const int tid  = threadIdx.x;
    const int wave = tid >> 6;
    const int lane = tid & 63;
    const int half = lane >> 5;
    const int hc   = lane & 31;

    // stride-33 pad: write banks (lane+c)%32 (2/bank, free), read banks (row+hc)%32 (2/bank, free)
    __shared__ float xpose[4][64 * 33];
    __shared__ int   omap[256];

    const size_t kP = (size_t)k * (size_t)P;

    for (int p0 = blockIdx.x * 256; p0 < P; p0 += gridDim.x * 256) {
        const int p = p0 + tid;
        const bool valid = p < P;

        __syncthreads();  // protect xpose/omap reuse across chunk iterations

        omap[tid] = valid ? out_map[kP + p] : -1;

        const int r = valid ? in_map[kP + p] : 0;
        const float4* frow = (const float4*)(features + (size_t)r * CI);
        float f[CI];
        #pragma unroll
        for (int q = 0; q < 8; ++q) {
            float4 v = frow[q];
            f[4*q+0] = v.x; f[4*q+1] = v.y; f[4*q+2] = v.z; f[4*q+3] = v.w;
        }

        float acc[CO];
        #pragma unroll
        for (int c = 0; c < CO; ++c) acc[c] = 0.f;

        #pragma unroll
        for (int i = 0; i < CI; ++i) {
            #pragma unroll
            for (int c = 0; c < CO; ++c) {
                acc[c] = fmaf(f[i], wk[i * CO + c], acc[c]);  // wk uniform -> SGPR operand
            }
        }

        // per-wave transpose so atomics are channel-contiguous per half-wave
        #pragma unroll
        for (int c = 0; c < CO; ++c)
            xpose[wave][lane * 33 + c] = acc[c];

        __syncthreads();

        // read back as (row-pair, channel): one atomic inst covers 2 rows x 128B
        for (int rr = 0; rr < 32; ++rr) {
            const int row = 2 * rr + half;            // 0..63 within this wave's chunk
            const int o = omap[wave * 64 + row];
            if (o >= 0) {
                float v = xpose[wave][row * 33 + hc];
                unsafeAtomicAdd(&out[(size_t)o * CO + hc], v);
            }
        }
    }
}

extern "C" void kernel_launch(void* const* d_in, const int* in_sizes, int n_in,
                              void* d_out, int out_size, void* d_ws, size_t ws_size,
                              hipStream_t stream) {
    const float* features = (const float*)d_in[0];
    const float* weight   = (const float*)d_in[1];
    const float* bias     = (const float*)d_in[2];
    const int*   in_map   = (const int*)d_in[3];
    const int*   out_map  = (const int*)d_in[4];

    const int K = in_sizes[1] / (CI * CO);           // 27
    const int P = in_sizes[3] / K;                   // 150000
    const int num_out = out_size / CO;               // 500000

    float* out = (float*)d_out;

    // 1) init with bias
    {
        int total4 = num_out * (CO / 4);             // float4 stores
        int threads = 256;
        int blocks = (total4 + threads - 1) / threads;
        hipLaunchKernelGGL(bias_init_kernel, dim3(blocks), dim3(threads), 0, stream,
                           out, bias, total4);
    }

    // 2) gather-GEMM-scatter
    {
        dim3 grid(128, K);
        hipLaunchKernelGGL(scatter_conv, grid, dim3(256), 0, stream,
                           features, weight, in_map, out_map, out, P);
    }
}

// Round 2
// 426.270 us; speedup vs baseline: 1.1650x; 1.1650x over previous
//
#include <hip/hip_runtime.h>
#include <hip/hip_bf16.h>

#define CI 32
#define CO 32

typedef __attribute__((ext_vector_type(8))) short bf16x8;
typedef __attribute__((ext_vector_type(4))) float f32x4;

__device__ inline short f2bf(float x) {
    __hip_bfloat16 h = __float2bfloat16(x);
    return *reinterpret_cast<short*>(&h);
}

// Kernel 1: out[o][c] = bias[c]  (fully initializes d_out; poison-safe)
__global__ void bias_init_kernel(float* __restrict__ out,
                                 const float* __restrict__ bias,
                                 int total4) {
    int idx = blockIdx.x * blockDim.x + threadIdx.x;
    if (idx >= total4) return;
    ((float4*)out)[idx] = ((const float4*)bias)[idx & 7];
}

// Kernel 2: per (k, 16-row group): D = gathered_A(16x32) @ wk(32x32), scattered
// with fp32 atomics straight from MFMA fragments.
// blockIdx.y = k -> B fragments are loop-invariant registers (8 VGPRs).
__global__ __launch_bounds__(256, 8) void scatter_conv_mfma(
    const float* __restrict__ features,
    const float* __restrict__ weight,
    const int* __restrict__ in_map,
    const int* __restrict__ out_map,
    float* __restrict__ out,
    int P, int groups)          // groups = ceil(P/16)
{
    const int k = blockIdx.y;
    const size_t kP = (size_t)k * (size_t)P;
    const int lane = threadIdx.x & 63;
    const int q = lane >> 4;        // lane quarter: k-chunk for A/B frags
    const int m = lane & 15;        // A row within group / D column (channel)

    // --- B fragments (loop-invariant): B[kk][n], n=m, kk=q*8+j ---
    const float* __restrict__ wk = weight + (size_t)k * (CI * CO);
    bf16x8 b0, b1;
    #pragma unroll
    for (int j = 0; j < 8; ++j) {
        int kk = q * 8 + j;
        b0[j] = f2bf(wk[kk * CO + m]);
        b1[j] = f2bf(wk[kk * CO + 16 + m]);
    }

    const int gwave   = (blockIdx.x * blockDim.x + threadIdx.x) >> 6;
    const int gstride = (gridDim.x * blockDim.x) >> 6;

    for (int g = gwave; g < groups; g += gstride) {
        const int pbase = g * 16;
        const int pm = pbase + m;

        // --- gather A: lane holds feature row in_map[pm], cols q*8 .. q*8+7 ---
        const int r = (pm < P) ? in_map[kP + pm] : 0;
        const f32x4* frow = (const f32x4*)(features + (size_t)r * CI + q * 8);
        f32x4 v0 = frow[0];
        f32x4 v1 = frow[1];
        bf16x8 a;
        a[0] = f2bf(v0.x); a[1] = f2bf(v0.y); a[2] = f2bf(v0.z); a[3] = f2bf(v0.w);
        a[4] = f2bf(v1.x); a[5] = f2bf(v1.y); a[6] = f2bf(v1.z); a[7] = f2bf(v1.w);
        if (pm >= P) a = (bf16x8){0,0,0,0,0,0,0,0};   // tail rows contribute 0

        f32x4 acc0 = {0.f, 0.f, 0.f, 0.f};
        f32x4 acc1 = {0.f, 0.f, 0.f, 0.f};
        acc0 = __builtin_amdgcn_mfma_f32_16x16x32_bf16(a, b0, acc0, 0, 0, 0);
        acc1 = __builtin_amdgcn_mfma_f32_16x16x32_bf16(a, b1, acc1, 0, 0, 0);

        // --- scatter: D row=(q*4+j), col=m.  One atomic inst = 4 rows x 64B. ---
        #pragma unroll
        for (int j = 0; j < 4; ++j) {
            const int row = q * 4 + j;
            const int pr = pbase + row;
            if (pr < P) {
                const int o = out_map[kP + pr];
                float* base = out + (size_t)o * CO + m;
                unsafeAtomicAdd(base,      acc0[j]);
                unsafeAtomicAdd(base + 16, acc1[j]);
            }
        }
    }
}

extern "C" void kernel_launch(void* const* d_in, const int* in_sizes, int n_in,
                              void* d_out, int out_size, void* d_ws, size_t ws_size,
                              hipStream_t stream) {
    const float* features = (const float*)d_in[0];
    const float* weight   = (const float*)d_in[1];
    const float* bias     = (const float*)d_in[2];
    const int*   in_map   = (const int*)d_in[3];
    const int*   out_map  = (const int*)d_in[4];

    const int K = in_sizes[1] / (CI * CO);           // 27
    const int P = in_sizes[3] / K;                   // 150000
    const int num_out = out_size / CO;               // 500000

    float* out = (float*)d_out;

    // 1) init with bias
    {
        int total4 = num_out * (CO / 4);             // float4 stores
        int threads = 256;
        int blocks = (total4 + threads - 1) / threads;
        hipLaunchKernelGGL(bias_init_kernel, dim3(blocks), dim3(threads), 0, stream,
                           out, bias, total4);
    }

    // 2) gather-MFMA-scatter
    {
        const int groups = (P + 15) / 16;            // 9375
        dim3 grid(160, K);                           // 160*4 waves per k-slice
        hipLaunchKernelGGL(scatter_conv_mfma, grid, dim3(256), 0, stream,
                           features, weight, in_map, out_map, out, P, groups);
    }
}